// Round 10
// baseline (218.099 us; speedup 1.0000x reference)
//
#include <hip/hip_runtime.h>
#include <stdint.h>

// ---------------------------------------------------------------------------
// GQA attention pipeline for MI355X (gfx950).
// S=2048, D_MODEL=2048, HEADS=32, HEAD_DIM=64, NKV=8 (group size 4).
// bf16 MFMA 16x16x32. Fragment layouts (learn_hip m89/m91):
//   A-frag: A[m = lane&15][k = (lane>>4)*8 + j]
//   B-frag: B^T[n = lane&15][k = (lane>>4)*8 + j]
//   C/D   : col = lane&15, row = (lane>>4)*4 + reg
// LDS tiles: slot(row,chunk)=chunk^(row&7) XOR swizzle (conflict-free b128).
// GEMMs: 128x128 block, 4 waves x 64x64 wave tile, BK=64, double-buffered
// global_load_lds staging, ONE barrier per K-step (0.5 ds_read/MFMA).
// Attention v4: transposed scores (S^T = K*Q^T) keep P in registers; key dim
// slot-permuted per 64-block, V^T written permuted from gemm_qkv epilogue.
// Static softmax shift (|s|<=8 after rmsnorm, exp2 domain). 4 dispatches.
// ---------------------------------------------------------------------------

typedef __bf16 bf16x8 __attribute__((ext_vector_type(8)));
typedef __bf16 bf16x4v __attribute__((ext_vector_type(4)));
typedef float f32x4 __attribute__((ext_vector_type(4)));

#define MFMA_BF16(a, b, c) __builtin_amdgcn_mfma_f32_16x16x32_bf16(a, b, c, 0, 0, 0)

#if __has_builtin(__builtin_amdgcn_exp2f)
#define EXP2F(x) __builtin_amdgcn_exp2f(x)
#else
#define EXP2F(x) __expf((x) * 0.69314718055994531f)
#endif

// q pre-scale: 1/sqrt(64)*log2(e); softmax shift in log2 domain: 8*log2(e)
#define QSCALE 0.18033688011112042f
#define SHIFT2 11.541560327111707f

__device__ __forceinline__ unsigned short f2bf(float f) {
  unsigned int u = __float_as_uint(f);
  u += 0x7fffu + ((u >> 16) & 1u);   // round-to-nearest-even
  return (unsigned short)(u >> 16);
}

// Async global->LDS, 16B per lane. LDS dest = wave-uniform base + lane*16.
__device__ __forceinline__ void gload_lds16(const unsigned short* gsrc,
                                            unsigned short* ldst) {
  __builtin_amdgcn_global_load_lds(
      (const __attribute__((address_space(1))) unsigned int*)gsrc,
      (__attribute__((address_space(3))) unsigned int*)ldst, 16, 0, 0);
}

// ---------------------------------------------------------------------------
// Kernel 1: weight transposes + x cast, ONE dispatch.
// grid (96, 32): bx<32 Wq | <40 Wk | <48 Wv | <80 Wo | <96 x-cast.
__global__ __launch_bounds__(256) void transpose_all(const float* __restrict__ Wq,
                                                     const float* __restrict__ Wk,
                                                     const float* __restrict__ Wv,
                                                     const float* __restrict__ Wo,
                                                     const float* __restrict__ x,
                                                     unsigned short* __restrict__ Wqkvt,
                                                     unsigned short* __restrict__ Wot,
                                                     unsigned short* __restrict__ xb) {
  int bx = blockIdx.x;
  int tid = threadIdx.x;
  if (bx >= 80) {                              // x fp32 -> bf16 cast
    int bid = (bx - 80) * 32 + blockIdx.y;     // 0..511, each 8192 elems
#pragma unroll
    for (int p = 0; p < 8; p++) {
      int i = bid * 8192 + p * 1024 + tid * 4;
      float4 v = *(const float4*)&x[i];
      ushort4 o;
      o.x = f2bf(v.x); o.y = f2bf(v.y); o.z = f2bf(v.z); o.w = f2bf(v.w);
      *(ushort4*)&xb[i] = o;
    }
    return;
  }
  const float* W;
  unsigned short* T;
  int N, nb;
  if (bx < 32)      { W = Wq; T = Wqkvt;                       N = 2048; nb = bx * 64; }
  else if (bx < 40) { W = Wk; T = Wqkvt + 2048 * 2048;         N = 512;  nb = (bx - 32) * 64; }
  else if (bx < 48) { W = Wv; T = Wqkvt + (size_t)2560 * 2048; N = 512;  nb = (bx - 40) * 64; }
  else              { W = Wo; T = Wot;                         N = 2048; nb = (bx - 48) * 64; }
  int kb = blockIdx.y * 64;
  __shared__ float tile[64][65];
#pragma unroll
  for (int i = 0; i < 16; i++) {
    int idx = tid + i * 256;
    int r = idx >> 6, c = idx & 63;
    tile[r][c] = W[(size_t)(kb + r) * N + nb + c];
  }
  __syncthreads();
#pragma unroll
  for (int i = 0; i < 8; i++) {
    int idx = tid + i * 256;
    int r = idx >> 5, cp = idx & 31;         // r = n-local, cp = k-pair
    ushort2 o;
    o.x = f2bf(tile[2 * cp][r]);
    o.y = f2bf(tile[2 * cp + 1][r]);
    *(ushort2*)&T[(size_t)(nb + r) * 2048 + kb + 2 * cp] = o;
  }
}

// ---------------------------------------------------------------------------
// 128x128 GEMM core: 4 waves in 2x2 (wave tile 64x64), BK=64, K=2048 fixed.
// Stage = A(128x64) | B(128x64) = 32 KB, x2 dbuf = 64 KB -> 2 blocks/CU.
// One __syncthreads per step; next tile prefetched right after the barrier.
// Per wave per step: 16 ds_read_b128, 32 MFMA, 8 gload_lds16.
#define GEMM_CORE128(A_, B_, m0_, n0_)                                         \
  int quad = lane >> 4, l16 = lane & 15;                                       \
  int wrow = (w & 1) * 64, wcol = (w >> 1) * 64;                               \
  int rsub = lane >> 3, csub = lane & 7;                                       \
  int chunk = csub ^ rsub;                                                     \
  int slotL = quad ^ (l16 & 7);                                                \
  const unsigned short* gS = (w < 2)                                           \
      ? &A_[(size_t)(m0_ + w * 64 + rsub) * 2048 + chunk * 8]                  \
      : &B_[(size_t)(n0_ + (w - 2) * 64 + rsub) * 2048 + chunk * 8];           \
  int lsOff = (w * 64) * 64 + lane * 8;                                        \
  f32x4 acc[4][4];                                                             \
  _Pragma("unroll") for (int i = 0; i < 4; i++)                                \
      _Pragma("unroll") for (int j = 0; j < 4; j++)                            \
          acc[i][j] = (f32x4){0.f, 0.f, 0.f, 0.f};                             \
  _Pragma("unroll") for (int c = 0; c < 8; c++)                                \
      gload_lds16(gS + (size_t)c * 8 * 2048, &Stage[0][0] + lsOff + c * 8 * 64); \
  for (int k0 = 0; k0 < 2048; k0 += 64) {                                      \
    __syncthreads();                                                           \
    const unsigned short* cur = &Stage[(k0 >> 6) & 1][0];                      \
    unsigned short* nxt = &Stage[((k0 >> 6) + 1) & 1][0];                      \
    if (k0 + 64 < 2048) {                                                      \
      _Pragma("unroll") for (int c = 0; c < 8; c++)                            \
          gload_lds16(gS + (size_t)c * 8 * 2048 + k0 + 64,                     \
                      nxt + lsOff + c * 8 * 64);                               \
    }                                                                          \
    const unsigned short* As = cur;                                            \
    const unsigned short* Bs = cur + 128 * 64;                                 \
    _Pragma("unroll") for (int kc = 0; kc < 2; kc++) {                         \
      int sl = (kc == 0) ? slotL : (slotL ^ 4);                                \
      bf16x8 af[4], bfr[4];                                                    \
      _Pragma("unroll") for (int i = 0; i < 4; i++)                            \
          af[i] = *(const bf16x8*)&As[(wrow + i * 16 + l16) * 64 + sl * 8];    \
      _Pragma("unroll") for (int j = 0; j < 4; j++)                            \
          bfr[j] = *(const bf16x8*)&Bs[(wcol + j * 16 + l16) * 64 + sl * 8];   \
      _Pragma("unroll") for (int i = 0; i < 4; i++)                            \
          _Pragma("unroll") for (int j = 0; j < 4; j++)                        \
              acc[i][j] = MFMA_BF16(af[i], bfr[j], acc[i][j]);                 \
    }                                                                          \
  }

// ---------------------------------------------------------------------------
// Kernel 2: qkv GEMM, fused RMSNorm+RoPE (q,k) and slot-permuted V^T write.
// grid (16 m-blocks fastest, 24 n-blocks): same-XCD blocks share the B strip.
// Wave = one head's 64 cols: hd = by*2 + (w>>1).
__global__ __launch_bounds__(256, 2) void gemm_qkv(const unsigned short* __restrict__ A,
                                                   const unsigned short* __restrict__ B,
                                                   const float* __restrict__ sinp,
                                                   const float* __restrict__ cosp,
                                                   const float* __restrict__ q_scale,
                                                   const float* __restrict__ k_scale,
                                                   unsigned short* __restrict__ qh,
                                                   unsigned short* __restrict__ kh,
                                                   unsigned short* __restrict__ vt) {
  __shared__ __align__(16) unsigned short Stage[2][256 * 64];
  int tid = threadIdx.x;
  int w = tid >> 6, lane = tid & 63;
  int m0 = blockIdx.x * 128;
  int n0 = blockIdx.y * 128;
  GEMM_CORE128(A, B, m0, n0)

  int hd = blockIdx.y * 2 + (w >> 1);
  if (hd < 40) {
    const float* scl = (hd < 32) ? q_scale : k_scale;
    float wsc[4];
#pragma unroll
    for (int j = 0; j < 4; j++) wsc[j] = scl[j * 16 + l16];
    float oscale = (hd < 32) ? QSCALE : 1.0f;
#pragma unroll
    for (int i = 0; i < 4; i++)
#pragma unroll
      for (int r = 0; r < 4; r++) {
        float ss = 0.f;
#pragma unroll
        for (int j = 0; j < 4; j++) ss += acc[i][j][r] * acc[i][j][r];
#pragma unroll
        for (int off = 8; off; off >>= 1) ss += __shfl_xor(ss, off);
        float inv = rsqrtf(ss * (1.f / 64.f) + 1e-6f);
        int s = m0 + wrow + i * 16 + quad * 4 + r;
        float xn[4];
#pragma unroll
        for (int j = 0; j < 4; j++) xn[j] = acc[i][j][r] * inv * wsc[j];
#pragma unroll
        for (int j = 0; j < 4; j++) {
          int d = j * 16 + l16;
          float rot = (j < 2) ? -xn[j + 2] : xn[j - 2];
          float out = (xn[j] * cosp[s * 64 + d] + rot * sinp[s * 64 + d]) * oscale;
          if (hd < 32) qh[(size_t)s * 2048 + hd * 64 + d] = f2bf(out);
          else         kh[(size_t)s * 512 + (hd - 32) * 64 + d] = f2bf(out);
        }
      }
  } else {
    // V^T direct write, slot-permuted: key = m0 + (w&1)*64 + i*16 + quad*4 + r
    // -> 64-block kb = w&1, t4 = i, slot = (i&1)*32 + quad*8 + (i>>1)*4 + r.
    int g = hd - 40;
    int base = m0 + (w & 1) * 64;
#pragma unroll
    for (int i = 0; i < 4; i++) {
      int slotb = (i & 1) * 32 + quad * 8 + (i >> 1) * 4;
#pragma unroll
      for (int j = 0; j < 4; j++) {
        bf16x4v pk;
#pragma unroll
        for (int r = 0; r < 4; r++) pk[r] = (__bf16)acc[i][j][r];
        *(bf16x4v*)&vt[(size_t)(g * 64 + j * 16 + l16) * 2048 + base + slotb] = pk;
      }
    }
  }
}

// ---------------------------------------------------------------------------
// Kernel 3: output GEMM. C fp32 = A[2048][2048] @ Bt[2048][2048] + bias.
__global__ __launch_bounds__(256, 2) void gemm_out(const unsigned short* __restrict__ A,
                                                   const unsigned short* __restrict__ B,
                                                   float* __restrict__ C,
                                                   const float* __restrict__ bias) {
  __shared__ __align__(16) unsigned short Stage[2][256 * 64];
  int tid = threadIdx.x;
  int w = tid >> 6, lane = tid & 63;
  int m0 = blockIdx.x * 128;
  int n0 = blockIdx.y * 128;
  GEMM_CORE128(A, B, m0, n0)

#pragma unroll
  for (int i = 0; i < 4; i++) {
    int row = m0 + wrow + i * 16 + quad * 4;
#pragma unroll
    for (int j = 0; j < 4; j++) {
      int col = n0 + wcol + j * 16 + l16;
      float b = bias[col];
#pragma unroll
      for (int r = 0; r < 4; r++)
        C[(size_t)(row + r) * 2048 + col] = acc[i][j][r] + b;
    }
  }
}

// ---------------------------------------------------------------------------
// Kernel 4: attention v4 — transposed scores, register P, no split,
// normalization fused. Grid (32 q-tiles swizzled, 32 heads); 4 waves; wave w
// owns q rows [q0+16w, +16). Per 64-key tile: stage K+V once per block,
// S^T = K*Q^T, exp2, PV B-frag from registers, O^T += V^T*P^T.
// End: scale by 1/l, transpose via reused Stage, write aout.
__global__ __launch_bounds__(256, 4) void attention(const unsigned short* __restrict__ qh,
                                                    const unsigned short* __restrict__ kh,
                                                    const unsigned short* __restrict__ vt,
                                                    unsigned short* __restrict__ aout) {
  int h = blockIdx.y;
  int g = h >> 2;
  int tile = (blockIdx.x + blockIdx.y) & 31;
  int q0 = tile * 64;
  int w = threadIdx.x >> 6;
  int lane = threadIdx.x & 63;
  int quad = lane >> 4;
  int l16 = lane & 15;
  int qrow0 = q0 + w * 16;

  __shared__ __align__(16) unsigned short Stage[8192];   // Ks(64x64) | Vs(64x64)
  unsigned short* Ks = Stage;
  unsigned short* Vs = Stage + 4096;

  int rsub = lane >> 3;
  int csub = lane & 7;
  int chunk = csub ^ rsub;                     // slot(row,c) = c ^ (row&7)

  const unsigned short* kg = &kh[(size_t)(w * 16 + rsub) * 512 + g * 64 + chunk * 8];
  const unsigned short* vg = &vt[(size_t)(g * 64 + w * 16 + rsub) * 2048 + chunk * 8];
  unsigned short* kl = Ks + (w * 16) * 64 + lane * 8;
  unsigned short* vl = Vs + (w * 16) * 64 + lane * 8;

  int posL = quad ^ (l16 & 7);
  int fL = l16 * 64 + posL * 8;
  int fH = l16 * 64 + (posL ^ 4) * 8;

  // Q as B-frag: lane n=l16 holds Q[qrow0+l16][d=quad*8+j] (+32 for chunk 1)
  bf16x8 bq0 = *(const bf16x8*)&qh[(size_t)(qrow0 + l16) * 2048 + h * 64 + quad * 8];
  bf16x8 bq1 = *(const bf16x8*)&qh[(size_t)(qrow0 + l16) * 2048 + h * 64 + 32 + quad * 8];

  f32x4 o[4];   // O^T d-tiles: o[jd][r] = O^T[d=jd*16+quad*4+r][q=qrow0+l16]
#pragma unroll
  for (int j = 0; j < 4; j++) o[j] = (f32x4){0.f, 0.f, 0.f, 0.f};
  float l_run = 0.f;   // all 16 scores of this lane share q = qrow0+l16

  int T = tile + 1;
  for (int it = 0; it < T; ++it) {
    int n0 = it << 6;
    __syncthreads();   // previous tile's readers done
    gload_lds16(kg + (size_t)n0 * 512, kl);
    gload_lds16(kg + (size_t)(n0 + 8) * 512, kl + 8 * 64);
    gload_lds16(vg + n0, vl);
    gload_lds16(vg + n0 + 8 * 2048, vl + 8 * 64);
    __syncthreads();   // staged tile visible

    f32x4 s[4];
#pragma unroll
    for (int t = 0; t < 4; ++t) {
      bf16x8 kfl = *(const bf16x8*)&Ks[t * 1024 + fL];
      bf16x8 kfh = *(const bf16x8*)&Ks[t * 1024 + fH];
      f32x4 zz = (f32x4){0.f, 0.f, 0.f, 0.f};
      zz = MFMA_BF16(kfl, bq0, zz);
      s[t] = MFMA_BF16(kfh, bq1, zz);
    }

    float pv[4][4];
    if (it == T - 1) {
      int qg = qrow0 + l16;
#pragma unroll
      for (int t = 0; t < 4; ++t)
#pragma unroll
        for (int r = 0; r < 4; ++r) {
          int key = n0 + t * 16 + quad * 4 + r;
          float p = (key <= qg) ? EXP2F(s[t][r] - SHIFT2) : 0.f;
          l_run += p;
          pv[t][r] = p;
        }
    } else {
#pragma unroll
      for (int t = 0; t < 4; ++t)
#pragma unroll
        for (int r = 0; r < 4; ++r) {
          float p = EXP2F(s[t][r] - SHIFT2);
          l_run += p;
          pv[t][r] = p;
        }
    }

    // PV B-frags straight from registers: chunk c elem j -> pv[(j>>2)*2+c][j&3]
    bf16x8 pf0, pf1;
#pragma unroll
    for (int j = 0; j < 4; ++j) {
      pf0[j] = (__bf16)pv[0][j];
      pf0[j + 4] = (__bf16)pv[2][j];
      pf1[j] = (__bf16)pv[1][j];
      pf1[j + 4] = (__bf16)pv[3][j];
    }

#pragma unroll
    for (int jd = 0; jd < 4; ++jd) {
      bf16x8 vfl = *(const bf16x8*)&Vs[jd * 1024 + fL];
      bf16x8 vfh = *(const bf16x8*)&Vs[jd * 1024 + fH];
      o[jd] = MFMA_BF16(vfl, pf0, o[jd]);
      o[jd] = MFMA_BF16(vfh, pf1, o[jd]);
    }
  }

  // full row-sum for q=qrow0+l16 (reduce across the 4 quads), normalize
  l_run += __shfl_xor(l_run, 16);
  l_run += __shfl_xor(l_run, 32);
  float linv = 1.f / l_run;

  // O^T -> LDS (wave-private region of Stage, after barrier) -> aout[q][...]
  __syncthreads();   // all waves done reading Ks/Vs
  unsigned short* Ob = Stage + w * (16 * 68);
#pragma unroll
  for (int jd = 0; jd < 4; ++jd) {
    bf16x4v pk;
#pragma unroll
    for (int r = 0; r < 4; ++r) pk[r] = (__bf16)(o[jd][r] * linv);
    *(bf16x4v*)&Ob[l16 * 68 + jd * 16 + quad * 4] = pk;
  }
  __threadfence_block();
#pragma unroll
  for (int rr = 0; rr < 2; ++rr) {
    int cidx = rr * 64 + lane;
    int row = cidx >> 3, ch = cidx & 7;
    bf16x8 v = *(const bf16x8*)&Ob[row * 68 + ch * 8];
    *(bf16x8*)&aout[(size_t)(qrow0 + row) * 2048 + h * 64 + ch * 8] = v;
  }
}

// ---------------------------------------------------------------------------
extern "C" void kernel_launch(void* const* d_in, const int* in_sizes, int n_in,
                              void* d_out, int out_size, void* d_ws, size_t ws_size,
                              hipStream_t stream) {
  (void)in_sizes; (void)n_in; (void)out_size; (void)ws_size;
  const float* x    = (const float*)d_in[0];
  const float* sinp = (const float*)d_in[1];
  const float* cosp = (const float*)d_in[2];
  // d_in[3] = mask (tril) — causality hardcoded.
  const float* Wq = (const float*)d_in[4];
  const float* Wk = (const float*)d_in[5];
  const float* Wv = (const float*)d_in[6];
  const float* Wo = (const float*)d_in[7];
  const float* bo = (const float*)d_in[8];
  const float* q_scale = (const float*)d_in[9];
  const float* k_scale = (const float*)d_in[10];
  float* outp = (float*)d_out;

  uint8_t* ws = (uint8_t*)d_ws;
  const size_t MB = 1024 * 1024;
  unsigned short* xb    = (unsigned short*)(ws);            //  8 MB
  unsigned short* Wqkvt = (unsigned short*)(ws + 8 * MB);   // 12 MB
  unsigned short* Wot   = (unsigned short*)(ws + 20 * MB);  //  8 MB
  unsigned short* qh    = (unsigned short*)(ws + 28 * MB);  //  8 MB
  unsigned short* kh    = (unsigned short*)(ws + 36 * MB);  //  2 MB
  unsigned short* vt    = (unsigned short*)(ws + 38 * MB);  //  2 MB (slot-permuted V^T)
  unsigned short* aout  = (unsigned short*)(ws + 40 * MB);  //  8 MB

  transpose_all<<<dim3(96, 32), 256, 0, stream>>>(Wq, Wk, Wv, Wo, x, Wqkvt, Wot, xb);
  gemm_qkv<<<dim3(16, 24), 256, 0, stream>>>(xb, Wqkvt, sinp, cosp, q_scale, k_scale,
                                             qh, kh, vt);
  attention<<<dim3(32, 32), 256, 0, stream>>>(qh, kh, vt, aout);
  gemm_out<<<dim3(16, 16), 256, 0, stream>>>(aout, Wot, outp, bo);
}

// Round 11
// 205.754 us; speedup vs baseline: 1.0600x; 1.0600x over previous
//
#include <hip/hip_runtime.h>
#include <stdint.h>

// ---------------------------------------------------------------------------
// GQA attention pipeline for MI355X (gfx950).
// S=2048, D_MODEL=2048, HEADS=32, HEAD_DIM=64, NKV=8 (group size 4).
// bf16 MFMA 16x16x32. Fragment layouts (learn_hip m89/m91):
//   A-frag: A[m = lane&15][k = (lane>>4)*8 + j]
//   B-frag: B^T[n = lane&15][k = (lane>>4)*8 + j]
//   C/D   : col = lane&15, row = (lane>>4)*4 + reg
// LDS tiles: slot(row,chunk)=chunk^(row&7) XOR swizzle (conflict-free b128).
// GEMMs: 64x128 block, 4 waves (2x2, wave tile 32x64), BK=64, double-buffered
// global_load_lds, one barrier per K-step (round-9 core; 128x128 regressed —
// at this problem size >=3 co-resident blocks/CU beats read-ratio).
// Attention v5: transposed scores (S^T=K*Q^T) keep P in registers; key dim
// slot-permuted per 64-block, V^T written permuted by gemm_qkv. TWO 64-key
// tiles staged per barrier pair (32 KB LDS) to halve barrier-drain events.
// Static softmax shift (|s|<=8 after rmsnorm, exp2 domain). 4 dispatches.
// ---------------------------------------------------------------------------

typedef __bf16 bf16x8 __attribute__((ext_vector_type(8)));
typedef __bf16 bf16x4v __attribute__((ext_vector_type(4)));
typedef float f32x4 __attribute__((ext_vector_type(4)));

#define MFMA_BF16(a, b, c) __builtin_amdgcn_mfma_f32_16x16x32_bf16(a, b, c, 0, 0, 0)

#if __has_builtin(__builtin_amdgcn_exp2f)
#define EXP2F(x) __builtin_amdgcn_exp2f(x)
#else
#define EXP2F(x) __expf((x) * 0.69314718055994531f)
#endif

// q pre-scale: 1/sqrt(64)*log2(e); softmax shift in log2 domain: 8*log2(e)
#define QSCALE 0.18033688011112042f
#define SHIFT2 11.541560327111707f

__device__ __forceinline__ unsigned short f2bf(float f) {
  unsigned int u = __float_as_uint(f);
  u += 0x7fffu + ((u >> 16) & 1u);   // round-to-nearest-even
  return (unsigned short)(u >> 16);
}

// Async global->LDS, 16B per lane. LDS dest = wave-uniform base + lane*16.
__device__ __forceinline__ void gload_lds16(const unsigned short* gsrc,
                                            unsigned short* ldst) {
  __builtin_amdgcn_global_load_lds(
      (const __attribute__((address_space(1))) unsigned int*)gsrc,
      (__attribute__((address_space(3))) unsigned int*)ldst, 16, 0, 0);
}

// ---------------------------------------------------------------------------
// Kernel 1: weight transposes + x cast, ONE dispatch.
// grid (96, 32): bx<32 Wq | <40 Wk | <48 Wv | <80 Wo | <96 x-cast.
__global__ __launch_bounds__(256) void transpose_all(const float* __restrict__ Wq,
                                                     const float* __restrict__ Wk,
                                                     const float* __restrict__ Wv,
                                                     const float* __restrict__ Wo,
                                                     const float* __restrict__ x,
                                                     unsigned short* __restrict__ Wqkvt,
                                                     unsigned short* __restrict__ Wot,
                                                     unsigned short* __restrict__ xb) {
  int bx = blockIdx.x;
  int tid = threadIdx.x;
  if (bx >= 80) {                              // x fp32 -> bf16 cast
    int bid = (bx - 80) * 32 + blockIdx.y;     // 0..511, each 8192 elems
#pragma unroll
    for (int p = 0; p < 8; p++) {
      int i = bid * 8192 + p * 1024 + tid * 4;
      float4 v = *(const float4*)&x[i];
      ushort4 o;
      o.x = f2bf(v.x); o.y = f2bf(v.y); o.z = f2bf(v.z); o.w = f2bf(v.w);
      *(ushort4*)&xb[i] = o;
    }
    return;
  }
  const float* W;
  unsigned short* T;
  int N, nb;
  if (bx < 32)      { W = Wq; T = Wqkvt;                       N = 2048; nb = bx * 64; }
  else if (bx < 40) { W = Wk; T = Wqkvt + 2048 * 2048;         N = 512;  nb = (bx - 32) * 64; }
  else if (bx < 48) { W = Wv; T = Wqkvt + (size_t)2560 * 2048; N = 512;  nb = (bx - 40) * 64; }
  else              { W = Wo; T = Wot;                         N = 2048; nb = (bx - 48) * 64; }
  int kb = blockIdx.y * 64;
  __shared__ float tile[64][65];
#pragma unroll
  for (int i = 0; i < 16; i++) {
    int idx = tid + i * 256;
    int r = idx >> 6, c = idx & 63;
    tile[r][c] = W[(size_t)(kb + r) * N + nb + c];
  }
  __syncthreads();
#pragma unroll
  for (int i = 0; i < 8; i++) {
    int idx = tid + i * 256;
    int r = idx >> 5, cp = idx & 31;         // r = n-local, cp = k-pair
    ushort2 o;
    o.x = f2bf(tile[2 * cp][r]);
    o.y = f2bf(tile[2 * cp + 1][r]);
    *(ushort2*)&T[(size_t)(nb + r) * 2048 + kb + 2 * cp] = o;
  }
}

// ---------------------------------------------------------------------------
// Double-buffered GEMM core: 4 waves, block 64(M)x128(N), wave tile 32x64
// (2x2 wave grid), BK=64, K=2048 fixed. One __syncthreads per K-step.
#define GEMM_DBUF(A_, B_, m0_, n0_)                                            \
  int quad = lane >> 4, l16 = lane & 15;                                       \
  int wrow = (w & 1) * 32, wcol = (w >> 1) * 64;                               \
  int rsub = lane >> 3, csub = lane & 7;                                       \
  int chunk = csub ^ rsub;                                                     \
  int slotL = quad ^ (l16 & 7);                                                \
  const unsigned short* gA = &A_[(size_t)(m0_ + w * 16 + rsub) * 2048 + chunk * 8]; \
  const unsigned short* gB = &B_[(size_t)(n0_ + w * 32 + rsub) * 2048 + chunk * 8]; \
  int laOff = (w * 16) * 64 + lane * 8;                                        \
  int lbOff = 64 * 64 + (w * 32) * 64 + lane * 8;                              \
  f32x4 acc[2][4];                                                             \
  _Pragma("unroll") for (int i = 0; i < 2; i++)                                \
      _Pragma("unroll") for (int j = 0; j < 4; j++)                            \
          acc[i][j] = (f32x4){0.f, 0.f, 0.f, 0.f};                             \
  {                                                                            \
    unsigned short* sp = &Stage[0][0];                                         \
    gload_lds16(gA, sp + laOff);                                               \
    gload_lds16(gA + 8 * 2048, sp + laOff + 8 * 64);                           \
    gload_lds16(gB, sp + lbOff);                                               \
    gload_lds16(gB + 8 * 2048, sp + lbOff + 8 * 64);                           \
    gload_lds16(gB + 16 * 2048, sp + lbOff + 16 * 64);                         \
    gload_lds16(gB + 24 * 2048, sp + lbOff + 24 * 64);                         \
  }                                                                            \
  for (int k0 = 0; k0 < 2048; k0 += 64) {                                      \
    __syncthreads();                                                           \
    const unsigned short* cur = &Stage[(k0 >> 6) & 1][0];                      \
    unsigned short* nxt = &Stage[((k0 >> 6) + 1) & 1][0];                      \
    if (k0 + 64 < 2048) {                                                      \
      int kn = k0 + 64;                                                        \
      gload_lds16(gA + kn, nxt + laOff);                                       \
      gload_lds16(gA + 8 * 2048 + kn, nxt + laOff + 8 * 64);                   \
      gload_lds16(gB + kn, nxt + lbOff);                                       \
      gload_lds16(gB + 8 * 2048 + kn, nxt + lbOff + 8 * 64);                   \
      gload_lds16(gB + 16 * 2048 + kn, nxt + lbOff + 16 * 64);                 \
      gload_lds16(gB + 24 * 2048 + kn, nxt + lbOff + 24 * 64);                 \
    }                                                                          \
    const unsigned short* As = cur;                                            \
    const unsigned short* Bs = cur + 64 * 64;                                  \
    bf16x8 af[2][2], bfr[4][2];                                                \
    _Pragma("unroll") for (int i = 0; i < 2; i++) {                            \
      int base = (wrow + i * 16 + l16) * 64;                                   \
      af[i][0] = *(const bf16x8*)&As[base + slotL * 8];                        \
      af[i][1] = *(const bf16x8*)&As[base + (slotL ^ 4) * 8];                  \
    }                                                                          \
    _Pragma("unroll") for (int j = 0; j < 4; j++) {                            \
      int base = (wcol + j * 16 + l16) * 64;                                   \
      bfr[j][0] = *(const bf16x8*)&Bs[base + slotL * 8];                       \
      bfr[j][1] = *(const bf16x8*)&Bs[base + (slotL ^ 4) * 8];                 \
    }                                                                          \
    _Pragma("unroll") for (int kc = 0; kc < 2; kc++)                           \
        _Pragma("unroll") for (int i = 0; i < 2; i++)                          \
            _Pragma("unroll") for (int j = 0; j < 4; j++)                      \
                acc[i][j] = MFMA_BF16(af[i][kc], bfr[j][kc], acc[i][j]);       \
  }

// ---------------------------------------------------------------------------
// Kernel 2: qkv GEMM, fused RMSNorm+RoPE (q,k) and slot-permuted V^T write.
// Wave pair (w=0,1 | 2,3) covers one head: hd = bx*2 + (w>>1).
__global__ __launch_bounds__(256, 3) void gemm_qkv(const unsigned short* __restrict__ A,
                                                   const unsigned short* __restrict__ B,
                                                   const float* __restrict__ sinp,
                                                   const float* __restrict__ cosp,
                                                   const float* __restrict__ q_scale,
                                                   const float* __restrict__ k_scale,
                                                   unsigned short* __restrict__ qh,
                                                   unsigned short* __restrict__ kh,
                                                   unsigned short* __restrict__ vt) {
  __shared__ __align__(16) unsigned short Stage[2][192 * 64];
  int tid = threadIdx.x;
  int w = tid >> 6, lane = tid & 63;
  int m0 = blockIdx.y * 64;
  int n0 = blockIdx.x * 128;
  GEMM_DBUF(A, B, m0, n0)

  int hd = blockIdx.x * 2 + (w >> 1);
  if (hd < 40) {
    const float* scl = (hd < 32) ? q_scale : k_scale;
    float wsc[4];
#pragma unroll
    for (int j = 0; j < 4; j++) wsc[j] = scl[j * 16 + l16];
    float oscale = (hd < 32) ? QSCALE : 1.0f;
#pragma unroll
    for (int i = 0; i < 2; i++)
#pragma unroll
      for (int r = 0; r < 4; r++) {
        float ss = 0.f;
#pragma unroll
        for (int j = 0; j < 4; j++) ss += acc[i][j][r] * acc[i][j][r];
#pragma unroll
        for (int off = 8; off; off >>= 1) ss += __shfl_xor(ss, off);
        float inv = rsqrtf(ss * (1.f / 64.f) + 1e-6f);
        int s = m0 + wrow + i * 16 + quad * 4 + r;
        float xn[4];
#pragma unroll
        for (int j = 0; j < 4; j++) xn[j] = acc[i][j][r] * inv * wsc[j];
#pragma unroll
        for (int j = 0; j < 4; j++) {
          int d = j * 16 + l16;
          float rot = (j < 2) ? -xn[j + 2] : xn[j - 2];
          float out = (xn[j] * cosp[s * 64 + d] + rot * sinp[s * 64 + d]) * oscale;
          if (hd < 32) qh[(size_t)s * 2048 + hd * 64 + d] = f2bf(out);
          else         kh[(size_t)s * 512 + (hd - 32) * 64 + d] = f2bf(out);
        }
      }
  } else {
    // V^T direct write, slot-permuted: key = m0 + wrow + i*16 + quad*4 + r,
    // t = (wrow+i*16)>>4, slot = (t&1)*32 + quad*8 + (t>>1)*4 + r.
    int g = hd - 40;
#pragma unroll
    for (int i = 0; i < 2; i++) {
      int t = (wrow + i * 16) >> 4;
      int slotb = (t & 1) * 32 + quad * 8 + (t >> 1) * 4;
#pragma unroll
      for (int j = 0; j < 4; j++) {
        bf16x4v pk;
#pragma unroll
        for (int r = 0; r < 4; r++) pk[r] = (__bf16)acc[i][j][r];
        *(bf16x4v*)&vt[(size_t)(g * 64 + j * 16 + l16) * 2048 + m0 + slotb] = pk;
      }
    }
  }
}

// ---------------------------------------------------------------------------
// Kernel 3: output GEMM. C fp32 = A[2048][2048] @ Bt[2048][2048] + bias.
__global__ __launch_bounds__(256, 3) void gemm_out(const unsigned short* __restrict__ A,
                                                   const unsigned short* __restrict__ B,
                                                   float* __restrict__ C,
                                                   const float* __restrict__ bias) {
  __shared__ __align__(16) unsigned short Stage[2][192 * 64];
  int tid = threadIdx.x;
  int w = tid >> 6, lane = tid & 63;
  int m0 = blockIdx.y * 64;
  int n0 = blockIdx.x * 128;
  GEMM_DBUF(A, B, m0, n0)

#pragma unroll
  for (int i = 0; i < 2; i++) {
    int row = m0 + wrow + i * 16 + quad * 4;
#pragma unroll
    for (int j = 0; j < 4; j++) {
      int col = n0 + wcol + j * 16 + l16;
      float b = bias[col];
#pragma unroll
      for (int r = 0; r < 4; r++)
        C[(size_t)(row + r) * 2048 + col] = acc[i][j][r] + b;
    }
  }
}

// ---------------------------------------------------------------------------
// Kernel 4: attention v5 — transposed scores, register P, two 64-key tiles
// per barrier pair. Grid (32 q-tiles swizzled, 32 heads); 4 waves; wave w
// owns q rows [q0+16w, +16).
__global__ __launch_bounds__(256, 4) void attention(const unsigned short* __restrict__ qh,
                                                    const unsigned short* __restrict__ kh,
                                                    const unsigned short* __restrict__ vt,
                                                    unsigned short* __restrict__ aout) {
  int h = blockIdx.y;
  int g = h >> 2;
  int tile = (blockIdx.x + blockIdx.y) & 31;
  int q0 = tile * 64;
  int w = threadIdx.x >> 6;
  int lane = threadIdx.x & 63;
  int quad = lane >> 4;
  int l16 = lane & 15;
  int qrow0 = q0 + w * 16;

  __shared__ __align__(16) unsigned short Stage[2][8192];  // 2 x (Ks|Vs), 32 KB

  int rsub = lane >> 3;
  int csub = lane & 7;
  int chunk = csub ^ rsub;                     // slot(row,c) = c ^ (row&7)

  const unsigned short* kg = &kh[(size_t)(w * 16 + rsub) * 512 + g * 64 + chunk * 8];
  const unsigned short* vg = &vt[(size_t)(g * 64 + w * 16 + rsub) * 2048 + chunk * 8];
  int klOff = (w * 16) * 64 + lane * 8;
  int vlOff = 4096 + (w * 16) * 64 + lane * 8;

  int posL = quad ^ (l16 & 7);
  int fL = l16 * 64 + posL * 8;
  int fH = l16 * 64 + (posL ^ 4) * 8;

  // Q as B-frag: lane n=l16 holds Q[qrow0+l16][d=quad*8+j] (+32 for chunk 1)
  bf16x8 bq0 = *(const bf16x8*)&qh[(size_t)(qrow0 + l16) * 2048 + h * 64 + quad * 8];
  bf16x8 bq1 = *(const bf16x8*)&qh[(size_t)(qrow0 + l16) * 2048 + h * 64 + 32 + quad * 8];

  f32x4 o[4];   // O^T d-tiles: o[jd][r] = O^T[d=jd*16+quad*4+r][q=qrow0+l16]
#pragma unroll
  for (int j = 0; j < 4; j++) o[j] = (f32x4){0.f, 0.f, 0.f, 0.f};
  float l_run = 0.f;   // all 16 scores of this lane share q = qrow0+l16

  int T = tile + 1;
  for (int it = 0; it < T; it += 2) {
    bool two = (it + 1 < T);
    __syncthreads();   // previous pair's readers done
    {
      int n0 = it << 6;
      unsigned short* sp = &Stage[0][0];
      gload_lds16(kg + (size_t)n0 * 512, sp + klOff);
      gload_lds16(kg + (size_t)(n0 + 8) * 512, sp + klOff + 8 * 64);
      gload_lds16(vg + n0, sp + vlOff);
      gload_lds16(vg + n0 + 8 * 2048, sp + vlOff + 8 * 64);
      if (two) {
        int n1 = n0 + 64;
        unsigned short* sp1 = &Stage[1][0];
        gload_lds16(kg + (size_t)n1 * 512, sp1 + klOff);
        gload_lds16(kg + (size_t)(n1 + 8) * 512, sp1 + klOff + 8 * 64);
        gload_lds16(vg + n1, sp1 + vlOff);
        gload_lds16(vg + n1 + 8 * 2048, sp1 + vlOff + 8 * 64);
      }
    }
    __syncthreads();   // staged tiles visible

#pragma unroll
    for (int u = 0; u < 2; ++u) {
      if (u && !two) break;
      int itc = it + u;
      int n0 = itc << 6;
      const unsigned short* Ks = &Stage[u][0];
      const unsigned short* Vs = &Stage[u][4096];

      f32x4 s[4];
#pragma unroll
      for (int t = 0; t < 4; ++t) {
        bf16x8 kfl = *(const bf16x8*)&Ks[t * 1024 + fL];
        bf16x8 kfh = *(const bf16x8*)&Ks[t * 1024 + fH];
        f32x4 zz = (f32x4){0.f, 0.f, 0.f, 0.f};
        zz = MFMA_BF16(kfl, bq0, zz);
        s[t] = MFMA_BF16(kfh, bq1, zz);
      }

      float pv[4][4];
      if (itc == T - 1) {
        int qg = qrow0 + l16;
#pragma unroll
        for (int t = 0; t < 4; ++t)
#pragma unroll
          for (int r = 0; r < 4; ++r) {
            int key = n0 + t * 16 + quad * 4 + r;
            float p = (key <= qg) ? EXP2F(s[t][r] - SHIFT2) : 0.f;
            l_run += p;
            pv[t][r] = p;
          }
      } else {
#pragma unroll
        for (int t = 0; t < 4; ++t)
#pragma unroll
          for (int r = 0; r < 4; ++r) {
            float p = EXP2F(s[t][r] - SHIFT2);
            l_run += p;
            pv[t][r] = p;
          }
      }

      // PV B-frags from registers: chunk c elem j -> pv[(j>>2)*2+c][j&3]
      bf16x8 pf0, pf1;
#pragma unroll
      for (int j = 0; j < 4; ++j) {
        pf0[j] = (__bf16)pv[0][j];
        pf0[j + 4] = (__bf16)pv[2][j];
        pf1[j] = (__bf16)pv[1][j];
        pf1[j + 4] = (__bf16)pv[3][j];
      }

#pragma unroll
      for (int jd = 0; jd < 4; ++jd) {
        bf16x8 vfl = *(const bf16x8*)&Vs[jd * 1024 + fL];
        bf16x8 vfh = *(const bf16x8*)&Vs[jd * 1024 + fH];
        o[jd] = MFMA_BF16(vfl, pf0, o[jd]);
        o[jd] = MFMA_BF16(vfh, pf1, o[jd]);
      }
    }
  }

  // full row-sum for q=qrow0+l16 (reduce across the 4 quads), normalize
  l_run += __shfl_xor(l_run, 16);
  l_run += __shfl_xor(l_run, 32);
  float linv = 1.f / l_run;

  // O^T -> LDS (wave-private region, after barrier) -> aout[q][...]
  __syncthreads();   // all waves done reading Stage
  unsigned short* Ob = &Stage[0][0] + w * (16 * 68);
#pragma unroll
  for (int jd = 0; jd < 4; ++jd) {
    bf16x4v pk;
#pragma unroll
    for (int r = 0; r < 4; ++r) pk[r] = (__bf16)(o[jd][r] * linv);
    *(bf16x4v*)&Ob[l16 * 68 + jd * 16 + quad * 4] = pk;
  }
  __threadfence_block();
#pragma unroll
  for (int rr = 0; rr < 2; ++rr) {
    int cidx = rr * 64 + lane;
    int row = cidx >> 3, ch = cidx & 7;
    bf16x8 v = *(const bf16x8*)&Ob[row * 68 + ch * 8];
    *(bf16x8*)&aout[(size_t)(qrow0 + row) * 2048 + h * 64 + ch * 8] = v;
  }
}

// ---------------------------------------------------------------------------
extern "C" void kernel_launch(void* const* d_in, const int* in_sizes, int n_in,
                              void* d_out, int out_size, void* d_ws, size_t ws_size,
                              hipStream_t stream) {
  (void)in_sizes; (void)n_in; (void)out_size; (void)ws_size;
  const float* x    = (const float*)d_in[0];
  const float* sinp = (const float*)d_in[1];
  const float* cosp = (const float*)d_in[2];
  // d_in[3] = mask (tril) — causality hardcoded.
  const float* Wq = (const float*)d_in[4];
  const float* Wk = (const float*)d_in[5];
  const float* Wv = (const float*)d_in[6];
  const float* Wo = (const float*)d_in[7];
  const float* bo = (const float*)d_in[8];
  const float* q_scale = (const float*)d_in[9];
  const float* k_scale = (const float*)d_in[10];
  float* outp = (float*)d_out;

  uint8_t* ws = (uint8_t*)d_ws;
  const size_t MB = 1024 * 1024;
  unsigned short* xb    = (unsigned short*)(ws);            //  8 MB
  unsigned short* Wqkvt = (unsigned short*)(ws + 8 * MB);   // 12 MB
  unsigned short* Wot   = (unsigned short*)(ws + 20 * MB);  //  8 MB
  unsigned short* qh    = (unsigned short*)(ws + 28 * MB);  //  8 MB
  unsigned short* kh    = (unsigned short*)(ws + 36 * MB);  //  2 MB
  unsigned short* vt    = (unsigned short*)(ws + 38 * MB);  //  2 MB (slot-permuted V^T)
  unsigned short* aout  = (unsigned short*)(ws + 40 * MB);  //  8 MB

  transpose_all<<<dim3(96, 32), 256, 0, stream>>>(Wq, Wk, Wv, Wo, x, Wqkvt, Wot, xb);
  gemm_qkv<<<dim3(24, 32), 256, 0, stream>>>(xb, Wqkvt, sinp, cosp, q_scale, k_scale,
                                             qh, kh, vt);
  attention<<<dim3(32, 32), 256, 0, stream>>>(qh, kh, vt, aout);
  gemm_out<<<dim3(16, 32), 256, 0, stream>>>(aout, Wot, outp, bo);
}